// Round 4
// baseline (162.554 us; speedup 1.0000x reference)
//
#include <hip/hip_runtime.h>
#include <cstdint>

// Problem constants (fixed by setup_inputs)
#define B_   4
#define N_   50000
#define K_   27
#define P_   (B_ * N_)           // 200000 points
#define L_   (P_ * K_)           // 5400000 flat entries (divisible by 64)
#define S_   130                 // per-dim encoding stride
#define PL_  (S_ * S_)           // 16900 plane stride
#define BB_  (S_ * S_ * S_)      // 2197000 per-batch block
#define KS_  (B_ * BB_)          // 8788000 possible keys
#define W_   (L_ / 64)           // 84375 bitmap words
#define NBW  ((W_ + 255) / 256)  // 330 word-scan blocks
#define BIG_ 0x7f000000          // empty marker (headroom for +26 of k-weights)

// ---------------------------------------------------------------------------
// init point table + trivial output fills (sequential, full-BW)
__global__ __launch_bounds__(256) void k_init_fill(int* __restrict__ P1,
                                                   int* __restrict__ out0,
                                                   int* __restrict__ out2) {
    int i = blockIdx.x * blockDim.x + threadIdx.x;
    if (i < KS_) P1[i] = BIG_;
    if (i < L_) {
        int p = i / K_;
        int k = i - p * K_;
        out0[i] = p - (p / N_) * N_;   // n
        out2[i] = k;
    }
}

// point table: P1[b, x+1, y+1, z+1] = min 32*p   (only 200k atomics)
__global__ __launch_bounds__(256) void k_ptab(const int* __restrict__ coords,
                                              const int* __restrict__ bidx,
                                              int* __restrict__ P1) {
    int p = blockIdx.x * blockDim.x + threadIdx.x;
    if (p >= P_) return;
    int b = bidx[p];
    int x = coords[3 * p + 0] + 1;
    int y = coords[3 * p + 1] + 1;
    int z = coords[3 * p + 2] + 1;
    int idx = ((b * S_ + x) * S_ + y) * S_ + z;
    atomicMin(&P1[idx], p << 5);
}

// separable min-plus stencils:  m(c) = min_off (32*p[c-off] + k(off)),
// k = 9(dx+1) + 3(dy+1) + (dz+1)   (lexicographic offset order)
__global__ __launch_bounds__(256) void k_minz(const int* __restrict__ src,
                                              int* __restrict__ dst) {
    int i = blockIdx.x * blockDim.x + threadIdx.x;
    if (i >= KS_) return;
    int z = i % S_;
    int v = src[i] + 1;
    if (z > 0)      v = min(v, src[i - 1] + 2);
    if (z < S_ - 1) v = min(v, src[i + 1]);      // +0
    dst[i] = v;
}

__global__ __launch_bounds__(256) void k_miny(const int* __restrict__ src,
                                              int* __restrict__ dst) {
    int i = blockIdx.x * blockDim.x + threadIdx.x;
    if (i >= KS_) return;
    int y = (i / S_) % S_;
    int v = src[i] + 3;
    if (y > 0)      v = min(v, src[i - S_] + 6);
    if (y < S_ - 1) v = min(v, src[i + S_]);     // +0
    dst[i] = v;
}

__global__ __launch_bounds__(256) void k_minx(const int* __restrict__ src,
                                              int* __restrict__ dst) {
    int i = blockIdx.x * blockDim.x + threadIdx.x;
    if (i >= KS_) return;
    int x = (i / PL_) % S_;
    int v = src[i] + 9;
    if (x > 0)      v = min(v, src[i - PL_] + 18);
    if (x < S_ - 1) v = min(v, src[i + PL_]);    // +0
    dst[i] = v;
}

// one random gather of M[cell(l)] per l; flags -> bitmap via ballot
__global__ __launch_bounds__(256) void k_flag_bitmap(const int* __restrict__ coords,
                                                     const int* __restrict__ bidx,
                                                     const int* __restrict__ koffs,
                                                     const int* __restrict__ M,
                                                     int* __restrict__ mArr,
                                                     unsigned long long* __restrict__ bitmap) {
    int l = blockIdx.x * blockDim.x + threadIdx.x;
    if (l >= L_) return;
    int p = l / K_;
    int k = l - p * K_;
    int b = bidx[p];
    int cx = coords[3 * p + 0] + koffs[3 * k + 0] + 1;
    int cy = coords[3 * p + 1] + koffs[3 * k + 1] + 1;
    int cz = coords[3 * p + 2] + koffs[3 * k + 2] + 1;
    int idx = ((b * S_ + cx) * S_ + cy) * S_ + cz;
    int m32 = M[idx];
    mArr[l] = m32;
    unsigned long long bal = __ballot(m32 == ((p << 5) | k));
    if ((threadIdx.x & 63) == 0) bitmap[l >> 6] = bal;
}

// per-word popcount + per-block exclusive scan over 84375 words
__global__ __launch_bounds__(256) void k_scan_words(const unsigned long long* __restrict__ bitmap,
                                                    int* __restrict__ wpre,
                                                    int* __restrict__ bsum) {
    __shared__ int sh[256];
    int w = blockIdx.x * 256 + threadIdx.x;
    int c = (w < W_) ? __popcll(bitmap[w]) : 0;
    sh[threadIdx.x] = c;
    __syncthreads();
    for (int off = 1; off < 256; off <<= 1) {
        int t = (threadIdx.x >= off) ? sh[threadIdx.x - off] : 0;
        __syncthreads();
        sh[threadIdx.x] += t;
        __syncthreads();
    }
    if (w < W_) wpre[w] = sh[threadIdx.x] - c;        // exclusive within block
    if (threadIdx.x == 255) bsum[blockIdx.x] = sh[255];
}

// single-block exclusive scan over the 330 block sums; emits num_unique
__global__ __launch_bounds__(512) void k_scan_block(int* __restrict__ bsum,
                                                    int* __restrict__ num_unique_out) {
    __shared__ int sh[512];
    int i = threadIdx.x;
    int v = (i < NBW) ? bsum[i] : 0;
    sh[i] = v;
    __syncthreads();
    for (int off = 1; off < 512; off <<= 1) {
        int t = (i >= off) ? sh[i - off] : 0;
        __syncthreads();
        sh[i] += t;
        __syncthreads();
    }
    if (i < NBW) bsum[i] = sh[i] - v;                 // global exclusive prefix
    if (i == 0) num_unique_out[0] = sh[511];
}

// rank via bitmap popcount (random reads hit ~1.3MB, L2-resident);
// valid outkey rows written once; tail rows (>= num_unique) written -1 here too.
__global__ __launch_bounds__(256) void k_finalize(const int* __restrict__ coords,
                                                  const int* __restrict__ koffs,
                                                  const unsigned long long* __restrict__ bitmap,
                                                  const int* __restrict__ wpre,
                                                  const int* __restrict__ bsum,
                                                  const int* __restrict__ numuniq,
                                                  int* __restrict__ out1,   // holds m32, becomes output_idx
                                                  int* __restrict__ outkey) {
    int l = blockIdx.x * blockDim.x + threadIdx.x;
    if (l >= L_) return;
    int m32 = out1[l];
    int m = (m32 >> 5) * K_ + (m32 & 31);
    int w = m >> 6;
    unsigned long long word = bitmap[w];
    unsigned long long mask = (1ull << (m & 63)) - 1ull;
    int rank = wpre[w] + bsum[w >> 8] + (int)__popcll(word & mask);
    if (m == l) {
        int p = l / K_;
        int k = l - p * K_;
        outkey[3 * rank + 0] = coords[3 * p + 0] + koffs[3 * k + 0];
        outkey[3 * rank + 1] = coords[3 * p + 1] + koffs[3 * k + 1];
        outkey[3 * rank + 2] = coords[3 * p + 2] + koffs[3 * k + 2];
    }
    out1[l] = rank;
    if (l >= numuniq[0]) {            // tail row l gets -1 (disjoint from valid rows)
        outkey[3 * l + 0] = -1;
        outkey[3 * l + 1] = -1;
        outkey[3 * l + 2] = -1;
    }
}

extern "C" void kernel_launch(void* const* d_in, const int* in_sizes, int n_in,
                              void* d_out, int out_size, void* d_ws, size_t ws_size,
                              hipStream_t stream) {
    const int* coords = (const int*)d_in[0];   // [B,N,3] int32
    const int* bidx   = (const int*)d_in[1];   // [B,N]   int32
    const int* koffs  = (const int*)d_in[2];   // [27,3]  int32

    int* out      = (int*)d_out;
    int* out0     = out;            // input_idx      [L]
    int* out1     = out + L_;       // output_idx     [L] (holds m32 first)
    int* out2     = out + 2 * L_;   // rel_pos_idx    [L]
    int* outkey   = out + 3 * L_;   // output_key     [L,3]
    int* numuniq  = out + 6 * L_;   // num_unique     [1]

    // ws (~36.2 MB): P1 | bitmap | wpre | bsum
    int* P1 = (int*)d_ws;                                         // KS_ ints
    unsigned long long* bitmap = (unsigned long long*)(P1 + KS_); // W_ u64 (8B aligned)
    int* wpre = (int*)(bitmap + W_);                              // W_ ints
    int* bsum = wpre + W_;                                        // NBW ints

    // stencil ping-pong scratch A lives in the (not-yet-written) outkey region:
    // KS_ = 8.788M ints <= 3*L_ = 16.2M ints; dead by the time finalize writes it.
    int* A = outkey;

    k_init_fill   <<<(KS_ + 255) / 256, 256, 0, stream>>>(P1, out0, out2);
    k_ptab        <<<(P_ + 255) / 256, 256, 0, stream>>>(coords, bidx, P1);
    k_minz        <<<(KS_ + 255) / 256, 256, 0, stream>>>(P1, A);   // P1 -> A
    k_miny        <<<(KS_ + 255) / 256, 256, 0, stream>>>(A, P1);   // A  -> P1
    k_minx        <<<(KS_ + 255) / 256, 256, 0, stream>>>(P1, A);   // P1 -> A (= M)
    k_flag_bitmap <<<(L_ + 255) / 256, 256, 0, stream>>>(coords, bidx, koffs, A, out1, bitmap);
    k_scan_words  <<<NBW, 256, 0, stream>>>(bitmap, wpre, bsum);
    k_scan_block  <<<1, 512, 0, stream>>>(bsum, numuniq);
    k_finalize    <<<(L_ + 255) / 256, 256, 0, stream>>>(coords, koffs, bitmap, wpre, bsum,
                                                         numuniq, out1, outkey);
}